// Round 5
// baseline (6111.549 us; speedup 1.0000x reference)
//
#include <hip/hip_runtime.h>

typedef unsigned short u16;

__device__ __forceinline__ float bf2f(u16 u) {
    return __uint_as_float(((unsigned int)u) << 16);
}

#define T_LEN 32768
#define YROW 65              // padded LDS row stride (words): banks (tt+ln)%32, 2-way = free
#define YBUF_S (64 * YROW)   // per-sample ybuf floats

struct LdBF16 {
    static __device__ __forceinline__ float ld(const void* p, int i) {
        return bf2f(((const u16*)p)[i]);
    }
};
struct LdF32 {
    static __device__ __forceinline__ float ld(const void* p, int i) {
        return ((const float*)p)[i];
    }
};

// quad_perm DPP move (VALU pipe, no LDS): lane reads quad-mate selected by CTRL
template <int CTRL>
__device__ __forceinline__ float qperm(float v) {
    return __int_as_float(__builtin_amdgcn_update_dpp(
        0, __float_as_int(v), CTRL, 0xF, 0xF, true));
}

__device__ __forceinline__ float rdl(float v, int lane) {
    return __int_as_float(__builtin_amdgcn_readlane(__float_as_int(v), lane));
}

// One wave handles TWO batch samples (independent recurrences interleaved to
// fill dependency-latency bubbles — single wave per CU has no other waves to
// hide latency with). lane = 4*j + q: quad j owns h-column j.
// q=0: reset gate, q=1: input gate, q=2: new gate, q=3: mirrors new gate.
// h is broadcast wave-uniform via v_readlane into SGPRs; gate handoffs are
// intra-quad DPP broadcasts (no DS ops on the critical path).
template <typename LD>
__device__ __forceinline__ void gru_run(
    const void* x,     const void* c,    const void* h0,
    const void* w1,    const void* b1,   const void* w2,    const void* b2,
    const void* pihw,  const void* pihb, const void* phhw,  const void* phhb,
    const void* pbihw, const void* pbihb,const void* pbhhw, const void* pbhhb,
    const void* oww,   const void* owb,  float* out, int b0, int ln, float* ybuf)
{
    const int j = ln >> 2;
    const int q = ln & 3;
    const int gate = (q < 3) ? q : 2;

    // Activation scales folded into weights at setup:
    //  r,i gates: acc = -log2e * z      -> sigmoid(z) = rcp(1+exp2(acc))
    //  n gate:    acc = -2log2e * (...) -> tanh = 2*rcp(1+exp2(acc)) - 1
    const float sc = (q < 2) ? -1.44269504f : -2.88539008f;
    const float sn = -2.88539008f;

    float W[2][16], wihA[2], biasA[2], wihN[2], bihN[2], owv[2], hl[2];
    float hs[2][16];

    #pragma unroll
    for (int s = 0; s < 2; ++s) {
        const int b = b0 + s;
        // ---- hypernetwork: cond MLP -> a2[8] (uniform; redundant per lane) ----
        float cv[8], a1[8], a2[8];
        #pragma unroll
        for (int n = 0; n < 8; ++n) cv[n] = LD::ld(c, b*8 + n);
        #pragma unroll
        for (int m = 0; m < 8; ++m) {
            float sacc = LD::ld(b1, m);
            #pragma unroll
            for (int n = 0; n < 8; ++n) sacc = fmaf(cv[n], LD::ld(w1, m*8 + n), sacc);
            a1[m] = (sacc >= 0.f) ? sacc : 0.1f * sacc;
        }
        #pragma unroll
        for (int m = 0; m < 8; ++m) {
            float sacc = LD::ld(b2, m);
            #pragma unroll
            for (int k = 0; k < 8; ++k) sacc = fmaf(a1[k], LD::ld(w2, m*8 + k), sacc);
            a2[m] = (sacc >= 0.f) ? sacc : 0.1f * sacc;
        }
        // projection helper: row of (w @ P.T + pb)
        auto proj = [&](const void* Wp, const void* Bv, int row) {
            float sacc = LD::ld(Bv, row);
            #pragma unroll
            for (int m = 0; m < 8; ++m) sacc = fmaf(a2[m], LD::ld(Wp, row*8 + m), sacc);
            return sacc;
        };

        #pragma unroll
        for (int r = 0; r < 16; ++r)
            W[s][r] = sc * proj(phhw, phhb, r*48 + gate*16 + j);

        const int gih = gate*16 + j;
        if (q < 2) {
            // r,i: fold x-weight + (b_ih + b_hh) into the accumulator init
            wihA[s]  = sc * proj(pihw, pihb, gih);
            biasA[s] = sc * (proj(pbihw, pbihb, gih) + proj(pbhhw, pbhhb, gih));
        } else {
            // n: b_hh_n must stay inside hh (it gets multiplied by resetgate)
            wihA[s]  = 0.f;
            biasA[s] = sc * proj(pbhhw, pbhhb, 32 + j);
        }
        // n-gate input projection, separate (NOT multiplied by resetgate)
        wihN[s] = sn * proj(pihw, pihb, 32 + j);
        bihN[s] = sn * proj(pbihw, pbihb, 32 + j);

        owv[s] = LD::ld(oww, j);
        hl[s]  = LD::ld(h0, b*16 + j);
        #pragma unroll
        for (int r = 0; r < 16; ++r)
            hs[s][r] = rdl(hl[s], 4*r);
    }
    const float obv = LD::ld(owb, 0);

    float xcur[2];
    #pragma unroll
    for (int s = 0; s < 2; ++s) xcur[s] = LD::ld(x, (b0+s)*T_LEN + ln);

    for (int t0 = 0; t0 < T_LEN; t0 += 64) {
        const int tn_ = t0 + 64;
        float xnxt[2];
        #pragma unroll
        for (int s = 0; s < 2; ++s)
            xnxt[s] = LD::ld(x, (b0+s)*T_LEN + ((tn_ < T_LEN) ? tn_ : 0) + ln);

        #pragma unroll 8
        for (int tt = 0; tt < 64; ++tt) {
            #pragma unroll
            for (int s = 0; s < 2; ++s) {
                const float xt  = rdl(xcur[s], tt);
                const float ipA = fmaf(xt, wihA[s], biasA[s]);   // off critical path
                const float ipn = fmaf(xt, wihN[s], bihN[s]);    // off critical path
                float a0  = fmaf(hs[s][0], W[s][0], ipA);
                float a1v = hs[s][1] * W[s][1];
                float a2v = hs[s][2] * W[s][2];
                float a3v = hs[s][3] * W[s][3];
                #pragma unroll
                for (int r = 4; r < 16; r += 4) {
                    a0  = fmaf(hs[s][r+0], W[s][r+0], a0);
                    a1v = fmaf(hs[s][r+1], W[s][r+1], a1v);
                    a2v = fmaf(hs[s][r+2], W[s][r+2], a2v);
                    a3v = fmaf(hs[s][r+3], W[s][r+3], a3v);
                }
                const float acc = (a0 + a1v) + (a2v + a3v);
                // q0 -> resetgate, q1 -> inputgate (q2/q3 garbage, unused)
                const float u   = __builtin_amdgcn_rcpf(1.f + __builtin_amdgcn_exp2f(acc));
                const float rg  = qperm<0x00>(u);            // resetgate to whole quad
                const float tno = fmaf(rg, acc, ipn);        // q2: scaled (ip_n + r*hh_n)
                const float u2  = __builtin_amdgcn_rcpf(1.f + __builtin_amdgcn_exp2f(tno));
                const float nn  = fmaf(2.f, u2, -1.f);       // tanh
                const float nb  = qperm<0xAA>(nn);           // newgate from q2
                const float ig  = qperm<0x55>(u);            // inputgate from q1
                hl[s] = fmaf(ig, hl[s] - nb, nb);            // h' = n + i*(h-n), quad-uniform
                #pragma unroll
                for (int r = 0; r < 16; ++r)
                    hs[s][r] = rdl(hl[s], 4*r);
                // hl quad-uniform: all 4 lanes write identical value, distinct slots.
                ybuf[s*YBUF_S + tt*YROW + ln] = hl[s] * owv[s];
            }
        }
        __syncthreads();   // order ybuf writes vs epilogue reads (single wave)
        #pragma unroll
        for (int s = 0; s < 2; ++s) {
            // lane l reduces timestep t0+l: y = ob + sum_j h_j*ow_j
            const float* row = ybuf + s*YBUF_S + ln*YROW;   // banks (ln+4j)%32: 2-way, free
            float p0 = row[0]  + row[4];
            float p1 = row[8]  + row[12];
            float p2 = row[16] + row[20];
            float p3 = row[24] + row[28];
            float p4 = row[32] + row[36];
            float p5 = row[40] + row[44];
            float p6 = row[48] + row[52];
            float p7 = row[56] + row[60];
            const float sum = ((p0+p1)+(p2+p3)) + ((p4+p5)+(p6+p7));
            out[(b0+s)*T_LEN + t0 + ln] = obv + sum;
        }
        __syncthreads();   // epilogue reads done before next chunk's writes
        xcur[0] = xnxt[0];
        xcur[1] = xnxt[1];
    }

    // h_last: [B,1,R] appended after y (f32)
    if (q == 0) {
        out[64 * T_LEN + (b0+0)*16 + j] = hl[0];
        out[64 * T_LEN + (b0+1)*16 + j] = hl[1];
    }
}

__global__ __launch_bounds__(64, 1) void hyper_gru_kernel(
    const void* x,     const void* c,    const void* h0,
    const void* w1,    const void* b1,   const void* w2,    const void* b2,
    const void* pihw,  const void* pihb, const void* phhw,  const void* phhb,
    const void* pbihw, const void* pbihb,const void* pbhhw, const void* pbhhb,
    const void* oww,   const void* owb,  float* out)
{
    const int b0 = blockIdx.x * 2;
    const int ln = threadIdx.x;
    __shared__ float ybuf[2 * YBUF_S];   // 2 samples x [64 timesteps][65 words]

    // ---- runtime dtype detection on x (f32 vs bf16) ----
    const u16 probe = ((const u16*)x)[2 * ln];
    const int e = (probe >> 7) & 0xFF;
    const unsigned long long bal = __ballot(e < 100 || e > 140);
    const bool is_f32 = (__popcll(bal) > 8);

    if (is_f32)
        gru_run<LdF32>(x, c, h0, w1, b1, w2, b2, pihw, pihb, phhw, phhb,
                       pbihw, pbihb, pbhhw, pbhhb, oww, owb, out, b0, ln, ybuf);
    else
        gru_run<LdBF16>(x, c, h0, w1, b1, w2, b2, pihw, pihb, phhw, phhb,
                        pbihw, pbihb, pbhhw, pbhhb, oww, owb, out, b0, ln, ybuf);
}

extern "C" void kernel_launch(void* const* d_in, const int* in_sizes, int n_in,
                              void* d_out, int out_size, void* d_ws, size_t ws_size,
                              hipStream_t stream) {
    (void)in_sizes; (void)n_in; (void)d_ws; (void)ws_size; (void)out_size;
    hipLaunchKernelGGL(hyper_gru_kernel, dim3(32), dim3(64), 0, stream,
        (const void*)d_in[0],  (const void*)d_in[1],  (const void*)d_in[2],
        (const void*)d_in[3],  (const void*)d_in[4],  (const void*)d_in[5],  (const void*)d_in[6],
        (const void*)d_in[7],  (const void*)d_in[8],  (const void*)d_in[9],  (const void*)d_in[10],
        (const void*)d_in[11], (const void*)d_in[12], (const void*)d_in[13], (const void*)d_in[14],
        (const void*)d_in[15], (const void*)d_in[16],
        (float*)d_out);
}

// Round 7
// 3489.797 us; speedup vs baseline: 1.7513x; 1.7513x over previous
//
#include <hip/hip_runtime.h>

#define T_LEN 32768
#define CHUNK 32
#define YROW 65   // row stride in words: write banks (tt+ln)%32 -> 2-way, free

// quad_perm DPP move (VALU pipe): lane reads quad-mate selected by CTRL
template <int CTRL>
__device__ __forceinline__ float qperm(float v) {
    return __int_as_float(__builtin_amdgcn_update_dpp(
        0, __float_as_int(v), CTRL, 0xF, 0xF, true));
}
__device__ __forceinline__ float rdl(float v, int lane) {
    return __int_as_float(__builtin_amdgcn_readlane(__float_as_int(v), lane));
}

// One wave per batch sample (latency-bound sequential scan: wall time =
// T * single-wave step time; minimize per-step issue + exposed latency).
// lane = 4*j + q: quad j owns h-column j. q=0: reset gate, q=1: input gate,
// q=2: new gate, q=3 mirrors new gate. h is broadcast wave-uniform via
// v_readlane (immediate lane select after full unroll); gate handoffs are
// intra-quad DPP broadcasts. Cross-lane y readout goes through LDS with
// explicit __syncthreads() — the barrier is REQUIRED for the compiler's
// memory model (cross-lane LDS RAW has no sync edge otherwise; removing it
// in r6 miscompiled), and costs ~2 cy/step amortized for a single wave.
__global__ __launch_bounds__(64, 1) void hyper_gru_kernel(
    const float* __restrict__ x,     const float* __restrict__ c,    const float* __restrict__ h0,
    const float* __restrict__ w1,    const float* __restrict__ b1,
    const float* __restrict__ w2,    const float* __restrict__ b2,
    const float* __restrict__ pihw,  const float* __restrict__ pihb,
    const float* __restrict__ phhw,  const float* __restrict__ phhb,
    const float* __restrict__ pbihw, const float* __restrict__ pbihb,
    const float* __restrict__ pbhhw, const float* __restrict__ pbhhb,
    const float* __restrict__ oww,   const float* __restrict__ owb,
    float* __restrict__ out)
{
    const int b  = blockIdx.x;
    const int ln = threadIdx.x;
    __shared__ float ybuf[CHUNK * YROW];   // h snapshots, one row per timestep

    const int j = ln >> 2;
    const int q = ln & 3;
    const int gate = (q < 3) ? q : 2;

    // ---- hypernetwork: cond MLP -> a2[8] (uniform; redundant per lane) ----
    float cv[8], a1[8], a2[8];
    #pragma unroll
    for (int n = 0; n < 8; ++n) cv[n] = c[b*8 + n];
    #pragma unroll
    for (int m = 0; m < 8; ++m) {
        float s = b1[m];
        #pragma unroll
        for (int n = 0; n < 8; ++n) s = fmaf(cv[n], w1[m*8 + n], s);
        a1[m] = (s >= 0.f) ? s : 0.1f * s;
    }
    #pragma unroll
    for (int m = 0; m < 8; ++m) {
        float s = b2[m];
        #pragma unroll
        for (int k = 0; k < 8; ++k) s = fmaf(a1[k], w2[m*8 + k], s);
        a2[m] = (s >= 0.f) ? s : 0.1f * s;
    }
    auto proj = [&](const float* W, const float* Bv, int row) {
        float s = Bv[row];
        #pragma unroll
        for (int m = 0; m < 8; ++m) s = fmaf(a2[m], W[row*8 + m], s);
        return s;
    };

    // Activation scales folded into weights:
    //  r,i: acc = -log2e * z        -> sigmoid(z) = rcp(1+exp2(acc))
    //  n:   acc = -2log2e * (...)   -> tanh = 2*rcp(1+exp2(acc)) - 1
    const float sc = (q < 2) ? -1.44269504f : -2.88539008f;
    const float sn = -2.88539008f;

    float W[16];
    #pragma unroll
    for (int r = 0; r < 16; ++r)
        W[r] = sc * proj(phhw, phhb, r*48 + gate*16 + j);

    const int gih = gate*16 + j;
    float wihA, biasA;
    if (q < 2) {   // r,i: fold x-weight + (b_ih + b_hh) into accumulator init
        wihA  = sc * proj(pihw, pihb, gih);
        biasA = sc * (proj(pbihw, pbihb, gih) + proj(pbhhw, pbhhb, gih));
    } else {       // n: b_hh_n stays inside hh (multiplied by resetgate)
        wihA  = 0.f;
        biasA = sc * proj(pbhhw, pbhhb, 32 + j);
    }
    const float wihN = sn * proj(pihw, pihb, 32 + j);
    const float bihN = sn * proj(pbihw, pbihb, 32 + j);

    float ow16[16];
    #pragma unroll
    for (int r = 0; r < 16; ++r) ow16[r] = oww[r];   // uniform, every lane
    const float obv = owb[0];

    float hl = h0[b*16 + j];
    float hs[16];
    #pragma unroll
    for (int r = 0; r < 16; ++r) hs[r] = rdl(hl, 4*r);

    float* wrow = ybuf + ln;                 // write: word ln + tt*YROW (imm offset)
    const float* rrow = ybuf + ln * YROW;    // epilogue read base (lanes 0..31)

    float xcur = x[b*T_LEN + (ln & 31)];
    for (int t0 = 0; t0 < T_LEN; t0 += CHUNK) {
        const int tn_ = t0 + CHUNK;
        const float xnxt = x[b*T_LEN + ((tn_ < T_LEN) ? tn_ : 0) + (ln & 31)];

        #pragma unroll
        for (int tt = 0; tt < CHUNK; ++tt) {
            const float xt  = rdl(xcur, tt);              // immediate lane select
            const float ipA = fmaf(xt, wihA, biasA);
            const float ipn = fmaf(xt, wihN, bihN);
            float a0  = fmaf(hs[0], W[0], ipA);
            float a1v = hs[1] * W[1];
            float a2v = hs[2] * W[2];
            float a3v = hs[3] * W[3];
            #pragma unroll
            for (int r = 4; r < 16; r += 4) {
                a0  = fmaf(hs[r+0], W[r+0], a0);
                a1v = fmaf(hs[r+1], W[r+1], a1v);
                a2v = fmaf(hs[r+2], W[r+2], a2v);
                a3v = fmaf(hs[r+3], W[r+3], a3v);
            }
            const float acc = (a0 + a1v) + (a2v + a3v);
            const float u   = __builtin_amdgcn_rcpf(1.f + __builtin_amdgcn_exp2f(acc));
            const float rg  = qperm<0x00>(u);             // resetgate -> quad
            const float tno = fmaf(rg, acc, ipn);
            const float u2  = __builtin_amdgcn_rcpf(1.f + __builtin_amdgcn_exp2f(tno));
            const float nn  = fmaf(2.f, u2, -1.f);        // tanh
            const float nb  = qperm<0xAA>(nn);            // newgate -> quad
            const float ig  = qperm<0x55>(u);             // inputgate -> quad
            hl = fmaf(ig, hl - nb, nb);                   // h' = n + i*(h-n), quad-uniform
            #pragma unroll
            for (int r = 0; r < 16; ++r) hs[r] = rdl(hl, 4*r);
            wrow[tt * YROW] = hl;   // ds_write_b32, imm offset; all lanes, distinct words
        }
        __syncthreads();   // REQUIRED: sync edge for cross-lane LDS RAW (see r6)
        // epilogue: lane l (<32) reduces timestep t0+l from q=0 slots (word 4r)
        if (ln < 32) {
            float y = obv;
            #pragma unroll
            for (int r = 0; r < 16; ++r) y = fmaf(rrow[4*r], ow16[r], y);
            out[b*T_LEN + t0 + ln] = y;
        }
        __syncthreads();   // epilogue reads done before next chunk's writes
        xcur = xnxt;
    }

    if (q == 0)
        out[64 * T_LEN + b*16 + j] = hl;   // h_last [B,1,R]
}

extern "C" void kernel_launch(void* const* d_in, const int* in_sizes, int n_in,
                              void* d_out, int out_size, void* d_ws, size_t ws_size,
                              hipStream_t stream) {
    (void)in_sizes; (void)n_in; (void)d_ws; (void)ws_size; (void)out_size;
    hipLaunchKernelGGL(hyper_gru_kernel, dim3(64), dim3(64), 0, stream,
        (const float*)d_in[0],  (const float*)d_in[1],  (const float*)d_in[2],
        (const float*)d_in[3],  (const float*)d_in[4],  (const float*)d_in[5],  (const float*)d_in[6],
        (const float*)d_in[7],  (const float*)d_in[8],  (const float*)d_in[9],  (const float*)d_in[10],
        (const float*)d_in[11], (const float*)d_in[12], (const float*)d_in[13], (const float*)d_in[14],
        (const float*)d_in[15], (const float*)d_in[16],
        (float*)d_out);
}

// Round 9
// 3130.777 us; speedup vs baseline: 1.9521x; 1.1147x over previous
//
#include <hip/hip_runtime.h>

#define T_LEN 32768
#define CHUNK 32
#define YROW 65   // row stride in words: write banks (tt+ln)%32 -> 2-way, free

typedef __fp16 half2v __attribute__((ext_vector_type(2)));   // matches builtin types

// quad_perm DPP move (VALU pipe): lane reads quad-mate selected by CTRL
template <int CTRL>
__device__ __forceinline__ float qperm(float v) {
    return __int_as_float(__builtin_amdgcn_update_dpp(
        0, __float_as_int(v), CTRL, 0xF, 0xF, true));
}
// DPP row_shl:4 — lane i reads lane i+4 within its 16-lane row
__device__ __forceinline__ float dpp_rowshl4(float v) {
    return __int_as_float(__builtin_amdgcn_update_dpp(
        0, __float_as_int(v), 0x104, 0xF, 0xF, true));
}
__device__ __forceinline__ float rdl(float v, int lane) {
    return __int_as_float(__builtin_amdgcn_readlane(__float_as_int(v), lane));
}

#if __has_builtin(__builtin_amdgcn_fdot2)
#define FDOT2(a, b, c) __builtin_amdgcn_fdot2((a), (b), (c), false)
#else
static __device__ __forceinline__ float fdot2_emul(half2v a, half2v b, float c) {
    return fmaf((float)a.x, (float)b.x, fmaf((float)a.y, (float)b.y, c));
}
#define FDOT2(a, b, c) fdot2_emul((a), (b), (c))
#endif

// Pack quad-0 h values into half2 pairs and broadcast wave-uniform:
// lane 4j holds h_j (q0). row_shl:4 brings h_{j+1}; cvt_pkrtz packs
// (h_{2k}, h_{2k+1}) at lanes 8k; 8 immediate readlanes -> uniform half2[8].
__device__ __forceinline__ void bcast_h(float hl, half2v hp[8]) {
    const float hr = dpp_rowshl4(hl);
    half2v pk = __builtin_amdgcn_cvt_pkrtz(hl, hr);
    int pi;
    __builtin_memcpy(&pi, &pk, 4);
    #pragma unroll
    for (int k = 0; k < 8; ++k) {
        int s = __builtin_amdgcn_readlane(pi, 8 * k);
        half2v hv;
        __builtin_memcpy(&hv, &s, 4);
        hp[k] = hv;
    }
}

// One wave per batch sample (latency/issue-bound sequential scan; wall time =
// T * per-step issue+chain of a single wave). lane = 4*j + q: quad j owns
// h-column j. q=0: reset gate, q=1: input gate, q=2: new gate (q3 mirrors).
// Broadcast h via f16-packed readlanes (8 instead of 16); matvec via
// v_dot2_f32_f16 (8 instead of 16 instrs). The sigmoid->tanh->update cascade
// runs entirely on q0 (acc_n arrives via one DPP issued in the sigmoid's
// shadow) so no DPP hop sits after the tanh. hl is architecturally valid ONLY
// on q0 lanes — all consumers (bcast_h lanes 8k, ybuf words 4r, h_last q==0)
// read q0 slots.
__global__ __launch_bounds__(64, 1) void hyper_gru_kernel(
    const float* __restrict__ x,     const float* __restrict__ c,    const float* __restrict__ h0,
    const float* __restrict__ w1,    const float* __restrict__ b1,
    const float* __restrict__ w2,    const float* __restrict__ b2,
    const float* __restrict__ pihw,  const float* __restrict__ pihb,
    const float* __restrict__ phhw,  const float* __restrict__ phhb,
    const float* __restrict__ pbihw, const float* __restrict__ pbihb,
    const float* __restrict__ pbhhw, const float* __restrict__ pbhhb,
    const float* __restrict__ oww,   const float* __restrict__ owb,
    float* __restrict__ out)
{
    const int b  = blockIdx.x;
    const int ln = threadIdx.x;
    __shared__ float ybuf[CHUNK * YROW];   // h snapshots, one row per timestep

    const int j = ln >> 2;
    const int q = ln & 3;
    const int gate = (q < 3) ? q : 2;

    // ---- hypernetwork: cond MLP -> a2[8] (uniform; redundant per lane) ----
    float cv[8], a1[8], a2[8];
    #pragma unroll
    for (int n = 0; n < 8; ++n) cv[n] = c[b*8 + n];
    #pragma unroll
    for (int m = 0; m < 8; ++m) {
        float s = b1[m];
        #pragma unroll
        for (int n = 0; n < 8; ++n) s = fmaf(cv[n], w1[m*8 + n], s);
        a1[m] = (s >= 0.f) ? s : 0.1f * s;
    }
    #pragma unroll
    for (int m = 0; m < 8; ++m) {
        float s = b2[m];
        #pragma unroll
        for (int k = 0; k < 8; ++k) s = fmaf(a1[k], w2[m*8 + k], s);
        a2[m] = (s >= 0.f) ? s : 0.1f * s;
    }
    auto proj = [&](const float* W, const float* Bv, int row) {
        float s = Bv[row];
        #pragma unroll
        for (int m = 0; m < 8; ++m) s = fmaf(a2[m], W[row*8 + m], s);
        return s;
    };

    // Activation scales folded into weights:
    //  r,i: acc = -log2e * z        -> sigmoid(z) = rcp(1+exp2(acc))
    //  n:   acc = -2log2e * (...)   -> tanh = 2*rcp(1+exp2(acc)) - 1
    const float sc = (q < 2) ? -1.44269504f : -2.88539008f;
    const float sn = -2.88539008f;

    float W[16];
    #pragma unroll
    for (int r = 0; r < 16; ++r)
        W[r] = sc * proj(phhw, phhb, r*48 + gate*16 + j);
    half2v Wp[8];
    #pragma unroll
    for (int k = 0; k < 8; ++k)
        Wp[k] = __builtin_amdgcn_cvt_pkrtz(W[2*k], W[2*k+1]);

    const int gih = gate*16 + j;
    float wihA, biasA;
    if (q < 2) {   // r,i: fold x-weight + (b_ih + b_hh) into accumulator init
        wihA  = sc * proj(pihw, pihb, gih);
        biasA = sc * (proj(pbihw, pbihb, gih) + proj(pbhhw, pbhhb, gih));
    } else {       // n: b_hh_n stays inside hh (multiplied by resetgate)
        wihA  = 0.f;
        biasA = sc * proj(pbhhw, pbhhb, 32 + j);
    }
    const float wihN = sn * proj(pihw, pihb, 32 + j);
    const float bihN = sn * proj(pbihw, pbihb, 32 + j);

    float ow16[16];
    #pragma unroll
    for (int r = 0; r < 16; ++r) ow16[r] = oww[r];   // uniform, every lane
    const float obv = owb[0];

    float hl = h0[b*16 + j];        // quad-uniform at start; q0-valid thereafter
    half2v hp[8];
    bcast_h(hl, hp);

    float* wrow = ybuf + ln;                 // write: word ln + tt*YROW (imm offset)
    const float* rrow = ybuf + ln * YROW;    // epilogue read base (lanes 0..31)

    float xcur = x[b*T_LEN + (ln & 31)];
    for (int t0 = 0; t0 < T_LEN; t0 += CHUNK) {
        const int tn_ = t0 + CHUNK;
        const float xnxt = x[b*T_LEN + ((tn_ < T_LEN) ? tn_ : 0) + (ln & 31)];

        #pragma unroll
        for (int tt = 0; tt < CHUNK; ++tt) {
            const float xt  = rdl(xcur, tt);              // immediate lane select
            const float ipA = fmaf(xt, wihA, biasA);
            const float ipn = fmaf(xt, wihN, bihN);
            // acc = scaled gate pre-activation, 4 dot2 chains of depth 2
            float c0 = FDOT2(hp[0], Wp[0], ipA);
            float c1 = FDOT2(hp[1], Wp[1], 0.f);
            float c2 = FDOT2(hp[2], Wp[2], 0.f);
            float c3 = FDOT2(hp[3], Wp[3], 0.f);
            c0 = FDOT2(hp[4], Wp[4], c0);
            c1 = FDOT2(hp[5], Wp[5], c1);
            c2 = FDOT2(hp[6], Wp[6], c2);
            c3 = FDOT2(hp[7], Wp[7], c3);
            const float acc = (c0 + c1) + (c2 + c3);
            // bring acc_n (q2) to the quad NOW — overlaps the sigmoid below
            const float accn = qperm<0xAA>(acc);
            const float u    = __builtin_amdgcn_rcpf(1.f + __builtin_amdgcn_exp2f(acc));
            const float ig   = qperm<0x55>(u);            // inputgate (q1) to quad
            // q0 continues locally: u = resetgate there
            const float tno = fmaf(u, accn, ipn);         // scaled tanh argument
            const float u2  = __builtin_amdgcn_rcpf(1.f + __builtin_amdgcn_exp2f(tno));
            const float nn  = fmaf(2.f, u2, -1.f);        // tanh
            hl = fmaf(ig, hl - nn, nn);                   // h' — valid on q0 lanes
            bcast_h(hl, hp);                              // dpp + cvt_pk + 8 rdl
            wrow[tt * YROW] = hl;   // ds_write_b32 imm offset; epilogue reads 4r (q0)
        }
        __syncthreads();   // REQUIRED: sync edge for cross-lane LDS RAW (see r6)
        // epilogue: lane l (<32) reduces timestep t0+l from q=0 slots (word 4r)
        if (ln < 32) {
            float y = obv;
            #pragma unroll
            for (int r = 0; r < 16; ++r) y = fmaf(rrow[4*r], ow16[r], y);
            out[b*T_LEN + t0 + ln] = y;
        }
        __syncthreads();   // epilogue reads done before next chunk's writes
        xcur = xnxt;
    }

    if (q == 0)
        out[64 * T_LEN + b*16 + j] = hl;   // h_last [B,1,R]
}

extern "C" void kernel_launch(void* const* d_in, const int* in_sizes, int n_in,
                              void* d_out, int out_size, void* d_ws, size_t ws_size,
                              hipStream_t stream) {
    (void)in_sizes; (void)n_in; (void)d_ws; (void)ws_size; (void)out_size;
    hipLaunchKernelGGL(hyper_gru_kernel, dim3(64), dim3(64), 0, stream,
        (const float*)d_in[0],  (const float*)d_in[1],  (const float*)d_in[2],
        (const float*)d_in[3],  (const float*)d_in[4],  (const float*)d_in[5],  (const float*)d_in[6],
        (const float*)d_in[7],  (const float*)d_in[8],  (const float*)d_in[9],  (const float*)d_in[10],
        (const float*)d_in[11], (const float*)d_in[12], (const float*)d_in[13], (const float*)d_in[14],
        (const float*)d_in[15], (const float*)d_in[16],
        (float*)d_out);
}